// Round 1
// baseline (429.502 us; speedup 1.0000x reference)
//
#include <hip/hip_runtime.h>

typedef short s16x8 __attribute__((ext_vector_type(8)));
typedef float f32x4 __attribute__((ext_vector_type(4)));

#define HWN 4096
#define CC  256
#define C2  128

static __device__ __forceinline__ unsigned short f2bf(float f) {
    union { float f; unsigned int u; } c; c.f = f;
    unsigned int u = c.u;
    unsigned int r = (u + 0x7fffu + ((u >> 16) & 1u)) >> 16;
    return (unsigned short)r;
}

// ---------------- K1: projections ----------------
// e1t[b][q][c2] = w_th @ x1 + b_th   (bf16, row-major over c2)
// e2t[b][q][c2] = w_pi @ x2 + b_pi   (bf16)
// g2c[b][c2][q] = w_g  @ x2 + b_g    (bf16, TRANSPOSED so PV B-frags read contiguous k)
__global__ __launch_bounds__(256) void k_proj(
    const float* __restrict__ x1, const float* __restrict__ x2,
    const float* __restrict__ w_th, const float* __restrict__ b_th,
    const float* __restrict__ w_pi, const float* __restrict__ b_pi,
    const float* __restrict__ w_g,  const float* __restrict__ b_g,
    unsigned short* __restrict__ e1t, unsigned short* __restrict__ e2t,
    unsigned short* __restrict__ g2c)
{
    __shared__ float xs[CC][64];
    const int tid = threadIdx.x;
    const int b  = blockIdx.x >> 6;
    const int q0 = (blockIdx.x & 63) * 64;
    const int q  = tid & 63;
    const int cg = __builtin_amdgcn_readfirstlane(tid >> 6);

    // ---- pass 1: x1 -> e1t ----
    for (int r = 0; r < 64; ++r) {
        int idx = r * 256 + tid;
        int c = idx >> 6, qq = idx & 63;
        xs[c][qq] = x1[((size_t)b * CC + c) * HWN + q0 + qq];
    }
    __syncthreads();
    #pragma unroll
    for (int j = 0; j < 8; ++j) {
        const int c2b = j * 16 + cg * 4;
        float a0 = b_th[c2b+0], a1 = b_th[c2b+1], a2 = b_th[c2b+2], a3 = b_th[c2b+3];
        for (int c = 0; c < CC; ++c) {
            float xv = xs[c][q];
            a0 += w_th[(c2b+0)*CC + c] * xv;
            a1 += w_th[(c2b+1)*CC + c] * xv;
            a2 += w_th[(c2b+2)*CC + c] * xv;
            a3 += w_th[(c2b+3)*CC + c] * xv;
        }
        ushort4 o; o.x = f2bf(a0); o.y = f2bf(a1); o.z = f2bf(a2); o.w = f2bf(a3);
        *(ushort4*)&e1t[((size_t)b*HWN + q0 + q)*C2 + c2b] = o;
    }
    __syncthreads();

    // ---- pass 2: x2 -> e2t and g2c ----
    for (int r = 0; r < 64; ++r) {
        int idx = r * 256 + tid;
        int c = idx >> 6, qq = idx & 63;
        xs[c][qq] = x2[((size_t)b * CC + c) * HWN + q0 + qq];
    }
    __syncthreads();
    #pragma unroll
    for (int j = 0; j < 8; ++j) {
        const int c2b = j * 16 + cg * 4;
        float a0 = b_pi[c2b+0], a1 = b_pi[c2b+1], a2 = b_pi[c2b+2], a3 = b_pi[c2b+3];
        for (int c = 0; c < CC; ++c) {
            float xv = xs[c][q];
            a0 += w_pi[(c2b+0)*CC + c] * xv;
            a1 += w_pi[(c2b+1)*CC + c] * xv;
            a2 += w_pi[(c2b+2)*CC + c] * xv;
            a3 += w_pi[(c2b+3)*CC + c] * xv;
        }
        ushort4 o; o.x = f2bf(a0); o.y = f2bf(a1); o.z = f2bf(a2); o.w = f2bf(a3);
        *(ushort4*)&e2t[((size_t)b*HWN + q0 + q)*C2 + c2b] = o;
    }
    #pragma unroll
    for (int j = 0; j < 8; ++j) {
        const int c2b = j * 16 + cg * 4;
        float a0 = b_g[c2b+0], a1 = b_g[c2b+1], a2 = b_g[c2b+2], a3 = b_g[c2b+3];
        for (int c = 0; c < CC; ++c) {
            float xv = xs[c][q];
            a0 += w_g[(c2b+0)*CC + c] * xv;
            a1 += w_g[(c2b+1)*CC + c] * xv;
            a2 += w_g[(c2b+2)*CC + c] * xv;
            a3 += w_g[(c2b+3)*CC + c] * xv;
        }
        g2c[((size_t)b*C2 + c2b+0)*HWN + q0 + q] = f2bf(a0);
        g2c[((size_t)b*C2 + c2b+1)*HWN + q0 + q] = f2bf(a1);
        g2c[((size_t)b*C2 + c2b+2)*HWN + q0 + q] = f2bf(a2);
        g2c[((size_t)b*C2 + c2b+3)*HWN + q0 + q] = f2bf(a3);
    }
}

// ---------------- K2: flash attention core ----------------
// Per block: 64 q-rows (4 waves x 16q). Loop over all 4096 k in tiles of 64.
// Per wave: scalar running max m_w, running sum s_w, unnormalized acc[16q][128c2].
__global__ __launch_bounds__(256, 2) void k_flash(
    const unsigned short* __restrict__ e1t, const unsigned short* __restrict__ e2t,
    const unsigned short* __restrict__ g2c,
    float* __restrict__ outp, float* __restrict__ ms)
{
    __shared__ unsigned short e2s[64][136];   // [k][c]  pad: 136*2=272B row (odd*16B)
    __shared__ unsigned short g2s[C2][72];    // [c2][k] pad: 144B row
    __shared__ unsigned short ps[4][16][72];  // per-wave P tile [q][k]

    const int tid  = threadIdx.x;
    const int b    = blockIdx.x >> 6;
    const int q0   = (blockIdx.x & 63) * 64;
    const int wid  = __builtin_amdgcn_readfirstlane(tid >> 6);
    const int lane = tid & 63;
    const int m16  = lane & 15;
    const int g    = lane >> 4;

    // hoisted A-fragments (e1 rows, K=128 total -> 4 ksteps of 32), kept in regs all kernel
    s16x8 afrag[4];
    {
        const unsigned short* p = e1t + ((size_t)b*HWN + q0 + wid*16 + m16) * C2 + g*8;
        #pragma unroll
        for (int kc = 0; kc < 4; ++kc) afrag[kc] = *(const s16x8*)(p + kc*32);
    }

    f32x4 acc[8];
    #pragma unroll
    for (int i = 0; i < 8; ++i) acc[i] = (f32x4){0.f,0.f,0.f,0.f};
    float m_w = -INFINITY;
    float s_w = 0.f;

    for (int it = 0; it < 64; ++it) {
        const int k0 = it * 64;
        __syncthreads();
        #pragma unroll
        for (int r = 0; r < 4; ++r) {   // stage e2 tile [64][128]
            int u = r*256 + tid;
            int row = u >> 4, c8 = u & 15;
            int4 v = *(const int4*)(e2t + ((size_t)b*HWN + k0 + row)*C2 + c8*8);
            *(int4*)&e2s[row][c8*8] = v;
        }
        #pragma unroll
        for (int r = 0; r < 4; ++r) {   // stage g2 tile [128][64]
            int u = r*256 + tid;
            int row = u >> 3, c8 = u & 7;
            int4 v = *(const int4*)(g2c + ((size_t)b*C2 + row)*HWN + k0 + c8*8);
            *(int4*)&g2s[row][c8*8] = v;
        }
        __syncthreads();

        // S[16q][64k] = e1 . e2^T
        f32x4 s[4];
        #pragma unroll
        for (int j = 0; j < 4; ++j) s[j] = (f32x4){0.f,0.f,0.f,0.f};
        #pragma unroll
        for (int j = 0; j < 4; ++j) {
            #pragma unroll
            for (int kc = 0; kc < 4; ++kc) {
                s16x8 bb = *(const s16x8*)&e2s[j*16 + m16][kc*32 + g*8];
                s[j] = __builtin_amdgcn_mfma_f32_16x16x32_bf16(afrag[kc], bb, s[j], 0, 0, 0);
            }
        }
        // wave-wide tile max
        float tm = -INFINITY;
        #pragma unroll
        for (int j = 0; j < 4; ++j) {
            #pragma unroll
            for (int r = 0; r < 4; ++r) tm = fmaxf(tm, s[j][r]);
        }
        #pragma unroll
        for (int off = 32; off >= 1; off >>= 1) tm = fmaxf(tm, __shfl_xor(tm, off));
        const float m_new = fmaxf(m_w, tm);
        const float scale = __expf(m_w - m_new);   // first iter: exp(-inf)=0
        m_w = m_new;
        s_w *= scale;
        #pragma unroll
        for (int i = 0; i < 8; ++i) {
            acc[i][0] *= scale; acc[i][1] *= scale;
            acc[i][2] *= scale; acc[i][3] *= scale;
        }
        // P = exp(S - m), bounce through per-wave LDS tile to re-fragment
        float psum = 0.f;
        #pragma unroll
        for (int j = 0; j < 4; ++j) {
            #pragma unroll
            for (int r = 0; r < 4; ++r) {
                float p = __expf(s[j][r] - m_new);
                psum += p;
                ps[wid][g*4 + r][j*16 + m16] = f2bf(p);  // [q within 16][k]
            }
        }
        s_w += psum;
        // PV: acc[16q][128c2] += P[16q][64k] * g2[64k][128c2]
        #pragma unroll
        for (int kk = 0; kk < 2; ++kk) {
            s16x8 pa = *(const s16x8*)&ps[wid][m16][kk*32 + g*8];
            #pragma unroll
            for (int fc = 0; fc < 8; ++fc) {
                s16x8 gb = *(const s16x8*)&g2s[fc*16 + m16][kk*32 + g*8];
                acc[fc] = __builtin_amdgcn_mfma_f32_16x16x32_bf16(pa, gb, acc[fc], 0, 0, 0);
            }
        }
    }

    // epilogue: reduce s_w across lanes, write (m,s) and unnormalized acc
    #pragma unroll
    for (int off = 32; off >= 1; off >>= 1) s_w += __shfl_xor(s_w, off);
    if (lane == 0) {
        ms[((size_t)b*256 + (q0>>4) + wid)*2 + 0] = m_w;
        ms[((size_t)b*256 + (q0>>4) + wid)*2 + 1] = s_w;
    }
    #pragma unroll
    for (int fc = 0; fc < 8; ++fc) {
        #pragma unroll
        for (int r = 0; r < 4; ++r) {
            outp[((size_t)b*HWN + q0 + wid*16 + g*4 + r)*C2 + fc*16 + m16] = acc[fc][r];
        }
    }
}

// ---------------- K3: per-batch (M, Z) from 256 (m,s) pairs ----------------
__global__ void k_mz(const float* __restrict__ ms, float* __restrict__ mz)
{
    __shared__ float rmax[4], rsum[4];
    const int b = blockIdx.x, tid = threadIdx.x;
    const int lane = tid & 63, wid = tid >> 6;
    float m = ms[((size_t)b*256 + tid)*2 + 0];
    float s = ms[((size_t)b*256 + tid)*2 + 1];
    float mm = m;
    #pragma unroll
    for (int off = 32; off >= 1; off >>= 1) mm = fmaxf(mm, __shfl_xor(mm, off));
    if (lane == 0) rmax[wid] = mm;
    __syncthreads();
    float M = fmaxf(fmaxf(rmax[0], rmax[1]), fmaxf(rmax[2], rmax[3]));
    float z = s * __expf(m - M);
    #pragma unroll
    for (int off = 32; off >= 1; off >>= 1) z += __shfl_xor(z, off);
    if (lane == 0) rsum[wid] = z;
    __syncthreads();
    if (tid == 0) { mz[b*2] = M; mz[b*2+1] = rsum[0]+rsum[1]+rsum[2]+rsum[3]; }
}

// ---------------- K4: normalize + final 1x1 conv + residual ----------------
__global__ __launch_bounds__(256) void k_out(
    const float* __restrict__ outp, const float* __restrict__ ms, const float* __restrict__ mz,
    const float* __restrict__ w_out, const float* __restrict__ b_out,
    const float* __restrict__ x1, float* __restrict__ out)
{
    __shared__ float ps2[C2][65];
    const int tid = threadIdx.x;
    const int b  = blockIdx.x >> 6;
    const int q0 = (blockIdx.x & 63) * 64;
    const float M = mz[b*2];
    const float invZ = 1.f / mz[b*2+1];
    #pragma unroll
    for (int r = 0; r < 32; ++r) {
        int u = r*256 + tid;
        int c2 = u & 127, qq = u >> 7;
        float mq = ms[((size_t)b*256 + (q0>>4) + (qq>>4))*2];
        float al = __expf(mq - M) * invZ;
        ps2[c2][qq] = outp[((size_t)b*HWN + q0 + qq)*C2 + c2] * al;
    }
    __syncthreads();
    const int q  = tid & 63;
    const int cg = __builtin_amdgcn_readfirstlane(tid >> 6);
    #pragma unroll
    for (int j = 0; j < 16; ++j) {
        const int co = j*16 + cg*4;
        float a0 = b_out[co+0], a1 = b_out[co+1], a2 = b_out[co+2], a3 = b_out[co+3];
        for (int c2 = 0; c2 < C2; ++c2) {
            float xv = ps2[c2][q];
            a0 += w_out[(co+0)*C2 + c2] * xv;
            a1 += w_out[(co+1)*C2 + c2] * xv;
            a2 += w_out[(co+2)*C2 + c2] * xv;
            a3 += w_out[(co+3)*C2 + c2] * xv;
        }
        size_t o0 = ((size_t)b*CC + co)*HWN + q0 + q;
        out[o0]         = a0 + x1[o0];
        out[o0 +   HWN] = a1 + x1[o0 +   HWN];
        out[o0 + 2*HWN] = a2 + x1[o0 + 2*HWN];
        out[o0 + 3*HWN] = a3 + x1[o0 + 3*HWN];
    }
}

extern "C" void kernel_launch(void* const* d_in, const int* in_sizes, int n_in,
                              void* d_out, int out_size, void* d_ws, size_t ws_size,
                              hipStream_t stream)
{
    const float* x1   = (const float*)d_in[0];
    const float* x2   = (const float*)d_in[1];
    const float* w_th = (const float*)d_in[2];
    const float* b_th = (const float*)d_in[3];
    const float* w_pi = (const float*)d_in[4];
    const float* b_pi = (const float*)d_in[5];
    const float* w_g  = (const float*)d_in[6];
    const float* b_g  = (const float*)d_in[7];
    const float* w_out= (const float*)d_in[8];
    const float* b_out= (const float*)d_in[9];
    float* out = (float*)d_out;

    char* ws = (char*)d_ws;
    unsigned short* e1t = (unsigned short*)(ws);                 // 8 MiB  bf16 [B][HW][C2]
    unsigned short* e2t = (unsigned short*)(ws + 8388608);       // 8 MiB  bf16 [B][HW][C2]
    unsigned short* g2c = (unsigned short*)(ws + 16777216);      // 8 MiB  bf16 [B][C2][HW]
    float*          outp= (float*)(ws + 25165824);               // 16 MiB f32  [B][HW][C2]
    float*          ms  = (float*)(ws + 41943040);               // 16 KiB f32  [B][256][2]
    float*          mz  = (float*)(ws + 41959424);               // 64 B   f32  [B][2]

    k_proj <<<dim3(512), dim3(256), 0, stream>>>(x1, x2, w_th, b_th, w_pi, b_pi, w_g, b_g,
                                                 e1t, e2t, g2c);
    k_flash<<<dim3(512), dim3(256), 0, stream>>>(e1t, e2t, g2c, outp, ms);
    k_mz   <<<dim3(8),   dim3(256), 0, stream>>>(ms, mz);
    k_out  <<<dim3(512), dim3(256), 0, stream>>>(outp, ms, mz, w_out, b_out, x1, out);
}

// Round 2
// 253.893 us; speedup vs baseline: 1.6917x; 1.6917x over previous
//
#include <hip/hip_runtime.h>

typedef unsigned short u16;
typedef short s16x8 __attribute__((ext_vector_type(8)));
typedef float f32x4 __attribute__((ext_vector_type(4)));

#define HWN 4096
#define CC  256
#define C2  128

static __device__ __forceinline__ u16 f2bf(float f) {
    union { float f; unsigned int u; } c; c.f = f;
    unsigned int u = c.u;
    unsigned int r = (u + 0x7fffu + ((u >> 16) & 1u)) >> 16;
    return (u16)r;
}

// ---------------- K0: convert weights to bf16 (all four are 32768 elements) ----
__global__ __launch_bounds__(256) void k_wcvt(
    const float* __restrict__ w_th, const float* __restrict__ w_pi,
    const float* __restrict__ w_g,  const float* __restrict__ w_out,
    u16* __restrict__ wthb, u16* __restrict__ wpib,
    u16* __restrict__ wgb,  u16* __restrict__ woutb)
{
    int i = blockIdx.x * 256 + threadIdx.x;
    wthb[i]  = f2bf(w_th[i]);
    wpib[i]  = f2bf(w_pi[i]);
    wgb[i]   = f2bf(w_g[i]);
    woutb[i] = f2bf(w_out[i]);
}

// ---------------- K1: MFMA projections ----------------
// e1t[b][q][c2] = w_th @ x1 + b_th   (bf16)
// e2t[b][q][c2] = w_pi @ x2 + b_pi   (bf16)
// g2c[b][c2][q] = w_g  @ x2 + b_g    (bf16, transposed via LDS bounce)
// A-frags transpose-loaded from x (lane m16 -> q, 8 dword loads down c, cvt to bf16).
// B-frags read from bf16 w[c2][c] rows (k-contiguous), L1/L2-hot.
__device__ __forceinline__ void load_afrag(const float* __restrict__ px, int g, s16x8 a[8]) {
    #pragma unroll
    for (int ks = 0; ks < 8; ++ks) {
        union { s16x8 v; u16 u[8]; } c;
        #pragma unroll
        for (int j = 0; j < 8; ++j)
            c.u[j] = f2bf(px[(size_t)(ks*32 + g*8 + j) * HWN]);
        a[ks] = c.v;
    }
}

__device__ __forceinline__ void proj_gemm(const s16x8 a[8], const u16* __restrict__ wb,
                                          const float* __restrict__ bias,
                                          int m16, int g, f32x4 acc[8]) {
    #pragma unroll
    for (int nb = 0; nb < 8; ++nb) {
        float bv = bias[nb*16 + m16];           // bias per D-column (= per lane m16)
        acc[nb] = (f32x4){bv, bv, bv, bv};
    }
    #pragma unroll
    for (int ks = 0; ks < 8; ++ks) {
        #pragma unroll
        for (int nb = 0; nb < 8; ++nb) {
            s16x8 bb = *(const s16x8*)&wb[(size_t)(nb*16 + m16)*CC + ks*32 + g*8];
            acc[nb] = __builtin_amdgcn_mfma_f32_16x16x32_bf16(a[ks], bb, acc[nb], 0, 0, 0);
        }
    }
}

__global__ __launch_bounds__(256) void k_projM(
    const float* __restrict__ x1, const float* __restrict__ x2,
    const u16* __restrict__ wthb, const float* __restrict__ b_th,
    const u16* __restrict__ wpib, const float* __restrict__ b_pi,
    const u16* __restrict__ wgb,  const float* __restrict__ b_g,
    u16* __restrict__ e1t, u16* __restrict__ e2t, u16* __restrict__ g2c)
{
    __shared__ u16 gs[C2][72];                  // g2 transpose bounce, pitch 144B (16B-aligned)
    const int tid  = threadIdx.x;
    const int b    = blockIdx.x >> 6;
    const int q0   = (blockIdx.x & 63) * 64;
    const int wid  = __builtin_amdgcn_readfirstlane(tid >> 6);
    const int lane = tid & 63;
    const int m16  = lane & 15;
    const int g    = lane >> 4;

    s16x8 a[8];
    f32x4 acc[8];

    // ---- theta: x1 -> e1t ----
    const float* px1 = x1 + (size_t)b*CC*HWN + q0 + wid*16 + m16;
    load_afrag(px1, g, a);
    proj_gemm(a, wthb, b_th, m16, g, acc);
    #pragma unroll
    for (int nb = 0; nb < 8; ++nb)
        #pragma unroll
        for (int r = 0; r < 4; ++r)
            e1t[((size_t)b*HWN + q0 + wid*16 + g*4 + r)*C2 + nb*16 + m16] = f2bf(acc[nb][r]);

    // ---- pi & g share x2 A-frags ----
    const float* px2 = x2 + (size_t)b*CC*HWN + q0 + wid*16 + m16;
    load_afrag(px2, g, a);
    proj_gemm(a, wpib, b_pi, m16, g, acc);
    #pragma unroll
    for (int nb = 0; nb < 8; ++nb)
        #pragma unroll
        for (int r = 0; r < 4; ++r)
            e2t[((size_t)b*HWN + q0 + wid*16 + g*4 + r)*C2 + nb*16 + m16] = f2bf(acc[nb][r]);

    proj_gemm(a, wgb, b_g, m16, g, acc);
    #pragma unroll
    for (int nb = 0; nb < 8; ++nb)
        #pragma unroll
        for (int r = 0; r < 4; ++r)
            gs[nb*16 + m16][wid*16 + g*4 + r] = f2bf(acc[nb][r]);
    __syncthreads();
    #pragma unroll
    for (int r = 0; r < 4; ++r) {               // coalesced copy-out [c2][q]
        int idx = r*256 + tid;
        int c2 = idx >> 3, q8 = idx & 7;
        int4 v = *(const int4*)&gs[c2][q8*8];
        *(int4*)&g2c[((size_t)b*C2 + c2)*HWN + q0 + q8*8] = v;
    }
}

// ---------------- K2: flash attention core (unchanged except bf16 epilogue) ----
__global__ __launch_bounds__(256, 2) void k_flash(
    const u16* __restrict__ e1t, const u16* __restrict__ e2t,
    const u16* __restrict__ g2c,
    u16* __restrict__ outpb, float* __restrict__ ms)
{
    __shared__ u16 e2s[64][136];
    __shared__ u16 g2s[C2][72];
    __shared__ u16 ps[4][16][72];

    const int tid  = threadIdx.x;
    const int b    = blockIdx.x >> 6;
    const int q0   = (blockIdx.x & 63) * 64;
    const int wid  = __builtin_amdgcn_readfirstlane(tid >> 6);
    const int lane = tid & 63;
    const int m16  = lane & 15;
    const int g    = lane >> 4;

    s16x8 afrag[4];
    {
        const u16* p = e1t + ((size_t)b*HWN + q0 + wid*16 + m16) * C2 + g*8;
        #pragma unroll
        for (int kc = 0; kc < 4; ++kc) afrag[kc] = *(const s16x8*)(p + kc*32);
    }

    f32x4 acc[8];
    #pragma unroll
    for (int i = 0; i < 8; ++i) acc[i] = (f32x4){0.f,0.f,0.f,0.f};
    float m_w = -INFINITY;
    float s_w = 0.f;

    for (int it = 0; it < 64; ++it) {
        const int k0 = it * 64;
        __syncthreads();
        #pragma unroll
        for (int r = 0; r < 4; ++r) {
            int u = r*256 + tid;
            int row = u >> 4, c8 = u & 15;
            int4 v = *(const int4*)(e2t + ((size_t)b*HWN + k0 + row)*C2 + c8*8);
            *(int4*)&e2s[row][c8*8] = v;
        }
        #pragma unroll
        for (int r = 0; r < 4; ++r) {
            int u = r*256 + tid;
            int row = u >> 3, c8 = u & 7;
            int4 v = *(const int4*)(g2c + ((size_t)b*C2 + row)*HWN + k0 + c8*8);
            *(int4*)&g2s[row][c8*8] = v;
        }
        __syncthreads();

        f32x4 s[4];
        #pragma unroll
        for (int j = 0; j < 4; ++j) s[j] = (f32x4){0.f,0.f,0.f,0.f};
        #pragma unroll
        for (int j = 0; j < 4; ++j) {
            #pragma unroll
            for (int kc = 0; kc < 4; ++kc) {
                s16x8 bb = *(const s16x8*)&e2s[j*16 + m16][kc*32 + g*8];
                s[j] = __builtin_amdgcn_mfma_f32_16x16x32_bf16(afrag[kc], bb, s[j], 0, 0, 0);
            }
        }
        float tm = -INFINITY;
        #pragma unroll
        for (int j = 0; j < 4; ++j) {
            #pragma unroll
            for (int r = 0; r < 4; ++r) tm = fmaxf(tm, s[j][r]);
        }
        #pragma unroll
        for (int off = 32; off >= 1; off >>= 1) tm = fmaxf(tm, __shfl_xor(tm, off));
        const float m_new = fmaxf(m_w, tm);
        const float scale = __expf(m_w - m_new);
        m_w = m_new;
        s_w *= scale;
        #pragma unroll
        for (int i = 0; i < 8; ++i) {
            acc[i][0] *= scale; acc[i][1] *= scale;
            acc[i][2] *= scale; acc[i][3] *= scale;
        }
        float psum = 0.f;
        #pragma unroll
        for (int j = 0; j < 4; ++j) {
            #pragma unroll
            for (int r = 0; r < 4; ++r) {
                float p = __expf(s[j][r] - m_new);
                psum += p;
                ps[wid][g*4 + r][j*16 + m16] = f2bf(p);
            }
        }
        s_w += psum;
        #pragma unroll
        for (int kk = 0; kk < 2; ++kk) {
            s16x8 pa = *(const s16x8*)&ps[wid][m16][kk*32 + g*8];
            #pragma unroll
            for (int fc = 0; fc < 8; ++fc) {
                s16x8 gb = *(const s16x8*)&g2s[fc*16 + m16][kk*32 + g*8];
                acc[fc] = __builtin_amdgcn_mfma_f32_16x16x32_bf16(pa, gb, acc[fc], 0, 0, 0);
            }
        }
    }

    #pragma unroll
    for (int off = 32; off >= 1; off >>= 1) s_w += __shfl_xor(s_w, off);
    if (lane == 0) {
        ms[((size_t)b*256 + (q0>>4) + wid)*2 + 0] = m_w;
        ms[((size_t)b*256 + (q0>>4) + wid)*2 + 1] = s_w;
    }
    const float inv_s = 1.f / s_w;
    #pragma unroll
    for (int fc = 0; fc < 8; ++fc) {
        #pragma unroll
        for (int r = 0; r < 4; ++r) {
            outpb[((size_t)b*HWN + q0 + wid*16 + g*4 + r)*C2 + fc*16 + m16] =
                f2bf(acc[fc][r] * inv_s);
        }
    }
}

// ---------------- K3: per-batch (M, Z) ----------------
__global__ void k_mz(const float* __restrict__ ms, float* __restrict__ mz)
{
    __shared__ float rmax[4], rsum[4];
    const int b = blockIdx.x, tid = threadIdx.x;
    const int lane = tid & 63, wid = tid >> 6;
    float m = ms[((size_t)b*256 + tid)*2 + 0];
    float s = ms[((size_t)b*256 + tid)*2 + 1];
    float mm = m;
    #pragma unroll
    for (int off = 32; off >= 1; off >>= 1) mm = fmaxf(mm, __shfl_xor(mm, off));
    if (lane == 0) rmax[wid] = mm;
    __syncthreads();
    float M = fmaxf(fmaxf(rmax[0], rmax[1]), fmaxf(rmax[2], rmax[3]));
    float z = s * __expf(m - M);
    #pragma unroll
    for (int off = 32; off >= 1; off >>= 1) z += __shfl_xor(z, off);
    if (lane == 0) rsum[wid] = z;
    __syncthreads();
    if (tid == 0) { mz[b*2] = M; mz[b*2+1] = rsum[0]+rsum[1]+rsum[2]+rsum[3]; }
}

// ---------------- K4: MFMA final conv, transposed output D[co][q] -------------
// A = w_out bf16 [co][c2] (k-contig), B = outpb bf16 [q][c2] (k-contig).
// Per-16q-row factor alpha = s_w*exp(m-M)/Z is wave-uniform, applied post-MFMA.
__global__ __launch_bounds__(256) void k_outM(
    const u16* __restrict__ outpb, const float* __restrict__ ms, const float* __restrict__ mz,
    const u16* __restrict__ woutb, const float* __restrict__ b_out,
    const float* __restrict__ x1, float* __restrict__ out)
{
    const int tid  = threadIdx.x;
    const int b    = blockIdx.x >> 6;
    const int q0   = (blockIdx.x & 63) * 64;
    const int wv   = __builtin_amdgcn_readfirstlane(tid >> 6);
    const int lane = tid & 63;
    const int m16  = lane & 15;
    const int g    = lane >> 4;
    const int q    = q0 + wv*16 + m16;

    s16x8 bfr[4];
    #pragma unroll
    for (int ks = 0; ks < 4; ++ks)
        bfr[ks] = *(const s16x8*)&outpb[((size_t)b*HWN + q)*C2 + ks*32 + g*8];

    f32x4 acc[16];
    #pragma unroll
    for (int cb = 0; cb < 16; ++cb) acc[cb] = (f32x4){0.f,0.f,0.f,0.f};
    #pragma unroll
    for (int ks = 0; ks < 4; ++ks) {
        #pragma unroll
        for (int cb = 0; cb < 16; ++cb) {
            s16x8 af = *(const s16x8*)&woutb[(size_t)(cb*16 + m16)*C2 + ks*32 + g*8];
            acc[cb] = __builtin_amdgcn_mfma_f32_16x16x32_bf16(af, bfr[ks], acc[cb], 0, 0, 0);
        }
    }

    const float M    = mz[b*2];
    const float invZ = 1.f / mz[b*2+1];
    const float mw   = ms[((size_t)b*256 + (q0>>4) + wv)*2 + 0];
    const float sw   = ms[((size_t)b*256 + (q0>>4) + wv)*2 + 1];
    const float alpha = sw * __expf(mw - M) * invZ;

    #pragma unroll
    for (int cb = 0; cb < 16; ++cb) {
        f32x4 bb = *(const f32x4*)&b_out[cb*16 + g*4];
        #pragma unroll
        for (int r = 0; r < 4; ++r) {
            int co = cb*16 + g*4 + r;
            size_t o = ((size_t)b*CC + co)*HWN + q;
            out[o] = alpha*acc[cb][r] + bb[r] + x1[o];
        }
    }
}

extern "C" void kernel_launch(void* const* d_in, const int* in_sizes, int n_in,
                              void* d_out, int out_size, void* d_ws, size_t ws_size,
                              hipStream_t stream)
{
    const float* x1   = (const float*)d_in[0];
    const float* x2   = (const float*)d_in[1];
    const float* w_th = (const float*)d_in[2];
    const float* b_th = (const float*)d_in[3];
    const float* w_pi = (const float*)d_in[4];
    const float* b_pi = (const float*)d_in[5];
    const float* w_g  = (const float*)d_in[6];
    const float* b_g  = (const float*)d_in[7];
    const float* w_out= (const float*)d_in[8];
    const float* b_out= (const float*)d_in[9];
    float* out = (float*)d_out;

    char* ws = (char*)d_ws;
    u16*   e1t  = (u16*)(ws);                    // 8 MiB  bf16 [B][HW][C2]
    u16*   e2t  = (u16*)(ws + 8388608);          // 8 MiB  bf16 [B][HW][C2]
    u16*   g2c  = (u16*)(ws + 16777216);         // 8 MiB  bf16 [B][C2][HW]
    u16*   outpb= (u16*)(ws + 25165824);         // 8 MiB  bf16 [B][HW][C2] (acc/s_w)
    float* ms   = (float*)(ws + 33554432);       // 16 KiB f32  [B][256][2]
    float* mz   = (float*)(ws + 33570816);       // 64 B   f32  [B][2]
    u16*   wthb = (u16*)(ws + 33571072);         // 64 KiB bf16 [C2][CC]
    u16*   wpib = (u16*)(ws + 33636608);         // 64 KiB
    u16*   wgb  = (u16*)(ws + 33702144);         // 64 KiB
    u16*   woutb= (u16*)(ws + 33767680);         // 64 KiB bf16 [CC][C2]

    k_wcvt <<<dim3(128), dim3(256), 0, stream>>>(w_th, w_pi, w_g, w_out, wthb, wpib, wgb, woutb);
    k_projM<<<dim3(512), dim3(256), 0, stream>>>(x1, x2, wthb, b_th, wpib, b_pi, wgb, b_g,
                                                 e1t, e2t, g2c);
    k_flash<<<dim3(512), dim3(256), 0, stream>>>(e1t, e2t, g2c, outpb, ms);
    k_mz   <<<dim3(8),   dim3(256), 0, stream>>>(ms, mz);
    k_outM <<<dim3(512), dim3(256), 0, stream>>>(outpb, ms, mz, woutb, b_out, x1, out);
}

// Round 3
// 207.728 us; speedup vs baseline: 2.0676x; 1.2222x over previous
//
#include <hip/hip_runtime.h>

typedef unsigned short u16;
typedef short s16x8 __attribute__((ext_vector_type(8)));
typedef float f32x4 __attribute__((ext_vector_type(4)));

#define HWN 4096
#define CC  256
#define C2  128

static __device__ __forceinline__ u16 f2bf(float f) {
    union { float f; unsigned int u; } c; c.f = f;
    unsigned int u = c.u;
    unsigned int r = (u + 0x7fffu + ((u >> 16) & 1u)) >> 16;
    return (u16)r;
}
static __device__ __forceinline__ float bf2f(u16 u) {
    union { unsigned int u; float f; } c; c.u = ((unsigned int)u) << 16; return c.f;
}

// ---------------- K0: convert weights to bf16 ----------------
__global__ __launch_bounds__(256) void k_wcvt(
    const float* __restrict__ w_th, const float* __restrict__ w_pi,
    const float* __restrict__ w_g,  const float* __restrict__ w_out,
    u16* __restrict__ wthb, u16* __restrict__ wpib,
    u16* __restrict__ wgb,  u16* __restrict__ woutb)
{
    int i = blockIdx.x * 256 + threadIdx.x;
    wthb[i]  = f2bf(w_th[i]);
    wpib[i]  = f2bf(w_pi[i]);
    wgb[i]   = f2bf(w_g[i]);
    woutb[i] = f2bf(w_out[i]);
}

// ---------------- K1: MFMA projections (unchanged from round 2) ----------------
__device__ __forceinline__ void load_afrag(const float* __restrict__ px, int g, s16x8 a[8]) {
    #pragma unroll
    for (int ks = 0; ks < 8; ++ks) {
        union { s16x8 v; u16 u[8]; } c;
        #pragma unroll
        for (int j = 0; j < 8; ++j)
            c.u[j] = f2bf(px[(size_t)(ks*32 + g*8 + j) * HWN]);
        a[ks] = c.v;
    }
}

__device__ __forceinline__ void proj_gemm(const s16x8 a[8], const u16* __restrict__ wb,
                                          const float* __restrict__ bias,
                                          int m16, int g, f32x4 acc[8]) {
    #pragma unroll
    for (int nb = 0; nb < 8; ++nb) {
        float bv = bias[nb*16 + m16];
        acc[nb] = (f32x4){bv, bv, bv, bv};
    }
    #pragma unroll
    for (int ks = 0; ks < 8; ++ks) {
        #pragma unroll
        for (int nb = 0; nb < 8; ++nb) {
            s16x8 bb = *(const s16x8*)&wb[(size_t)(nb*16 + m16)*CC + ks*32 + g*8];
            acc[nb] = __builtin_amdgcn_mfma_f32_16x16x32_bf16(a[ks], bb, acc[nb], 0, 0, 0);
        }
    }
}

__global__ __launch_bounds__(256) void k_projM(
    const float* __restrict__ x1, const float* __restrict__ x2,
    const u16* __restrict__ wthb, const float* __restrict__ b_th,
    const u16* __restrict__ wpib, const float* __restrict__ b_pi,
    const u16* __restrict__ wgb,  const float* __restrict__ b_g,
    u16* __restrict__ e1t, u16* __restrict__ e2t, u16* __restrict__ g2c)
{
    __shared__ u16 gs[C2][72];
    const int tid  = threadIdx.x;
    const int b    = blockIdx.x >> 6;
    const int q0   = (blockIdx.x & 63) * 64;
    const int wid  = __builtin_amdgcn_readfirstlane(tid >> 6);
    const int lane = tid & 63;
    const int m16  = lane & 15;
    const int g    = lane >> 4;

    s16x8 a[8];
    f32x4 acc[8];

    const float* px1 = x1 + (size_t)b*CC*HWN + q0 + wid*16 + m16;
    load_afrag(px1, g, a);
    proj_gemm(a, wthb, b_th, m16, g, acc);
    #pragma unroll
    for (int nb = 0; nb < 8; ++nb)
        #pragma unroll
        for (int r = 0; r < 4; ++r)
            e1t[((size_t)b*HWN + q0 + wid*16 + g*4 + r)*C2 + nb*16 + m16] = f2bf(acc[nb][r]);

    const float* px2 = x2 + (size_t)b*CC*HWN + q0 + wid*16 + m16;
    load_afrag(px2, g, a);
    proj_gemm(a, wpib, b_pi, m16, g, acc);
    #pragma unroll
    for (int nb = 0; nb < 8; ++nb)
        #pragma unroll
        for (int r = 0; r < 4; ++r)
            e2t[((size_t)b*HWN + q0 + wid*16 + g*4 + r)*C2 + nb*16 + m16] = f2bf(acc[nb][r]);

    proj_gemm(a, wgb, b_g, m16, g, acc);
    #pragma unroll
    for (int nb = 0; nb < 8; ++nb)
        #pragma unroll
        for (int r = 0; r < 4; ++r)
            gs[nb*16 + m16][wid*16 + g*4 + r] = f2bf(acc[nb][r]);
    __syncthreads();
    #pragma unroll
    for (int r = 0; r < 4; ++r) {
        int idx = r*256 + tid;
        int c2 = idx >> 3, q8 = idx & 7;
        int4 v = *(const int4*)&gs[c2][q8*8];
        *(int4*)&g2c[((size_t)b*C2 + c2)*HWN + q0 + q8*8] = v;
    }
}

// ---------------- K2: flash core — 32 q/wave, k-split 2, XOR-swizzled LDS ------
// Block: 4 waves x 32q = 128 q-rows; 32 k-tiles of 64 per segment.
// B-frags (bb/gb) are read once and feed BOTH q-halves' MFMAs (2x LDS intensity).
__global__ __launch_bounds__(256, 2) void k_flash(
    const u16* __restrict__ e1t, const u16* __restrict__ e2t,
    const u16* __restrict__ g2c,
    u16* __restrict__ outp0, u16* __restrict__ outp1, float* __restrict__ ms)
{
    __shared__ u16 e2s[64*128];     // [k][c2], rows 256B, swizzled
    __shared__ u16 g2s[128*64];     // [c2][k], rows 128B, swizzled
    __shared__ u16 ps[4][32*64];    // per-wave [q][k], rows 128B, swizzled

    const int tid  = threadIdx.x;
    const int b    = blockIdx.x >> 6;
    const int qb   = (blockIdx.x >> 1) & 31;
    const int seg  = blockIdx.x & 1;
    const int q0   = qb * 128;
    const int wid  = __builtin_amdgcn_readfirstlane(tid >> 6);
    const int lane = tid & 63;
    const int m16  = lane & 15;
    const int g    = lane >> 4;
    const int sw16 = (m16 & 7) << 3;    // u16-index swizzle (== byte ^ ((row&7)<<4))

    // A-frags: 2 q-halves x 4 ksteps, in regs for whole kernel
    s16x8 af[2][4];
    #pragma unroll
    for (int h = 0; h < 2; ++h) {
        const u16* p = e1t + ((size_t)b*HWN + q0 + wid*32 + h*16 + m16)*C2 + g*8;
        #pragma unroll
        for (int kc = 0; kc < 4; ++kc) af[h][kc] = *(const s16x8*)(p + kc*32);
    }

    f32x4 acc[2][8];
    #pragma unroll
    for (int h = 0; h < 2; ++h)
        #pragma unroll
        for (int i = 0; i < 8; ++i) acc[h][i] = (f32x4){0.f,0.f,0.f,0.f};
    float m_w = -INFINITY, s_w = 0.f;

    const u16* e2base = e2t + (size_t)b*HWN*C2;
    const u16* g2base = g2c + (size_t)b*C2*HWN;
    const int er_row = tid >> 4, er_c16 = tid & 15;   // e2s staging map
    const int gr_row = tid >> 3, gr_c8  = tid & 7;    // g2s staging map

    for (int it = 0; it < 32; ++it) {
        const int k0 = seg*2048 + it*64;
        __syncthreads();
        #pragma unroll
        for (int r = 0; r < 4; ++r) {           // stage e2 [64][128]
            int row = r*16 + er_row;
            int4 v = *(const int4*)(e2base + (size_t)(k0 + row)*C2 + er_c16*8);
            *(int4*)&e2s[(row*128 + er_c16*8) ^ ((row&7)<<3)] = v;
        }
        #pragma unroll
        for (int r = 0; r < 4; ++r) {           // stage g2 [128][64]
            int row = r*32 + gr_row;
            int4 v = *(const int4*)(g2base + (size_t)row*HWN + k0 + gr_c8*8);
            *(int4*)&g2s[(row*64 + gr_c8*8) ^ ((row&7)<<3)] = v;
        }
        __syncthreads();

        // S[32q][64k]
        f32x4 s[2][4];
        #pragma unroll
        for (int h = 0; h < 2; ++h)
            #pragma unroll
            for (int j = 0; j < 4; ++j) s[h][j] = (f32x4){0.f,0.f,0.f,0.f};
        #pragma unroll
        for (int j = 0; j < 4; ++j) {
            #pragma unroll
            for (int kc = 0; kc < 4; ++kc) {
                s16x8 bb = *(const s16x8*)&e2s[((j*16+m16)*128 + kc*32 + g*8) ^ sw16];
                s[0][j] = __builtin_amdgcn_mfma_f32_16x16x32_bf16(af[0][kc], bb, s[0][j], 0, 0, 0);
                s[1][j] = __builtin_amdgcn_mfma_f32_16x16x32_bf16(af[1][kc], bb, s[1][j], 0, 0, 0);
            }
        }
        float tm = -INFINITY;
        #pragma unroll
        for (int h = 0; h < 2; ++h)
            #pragma unroll
            for (int j = 0; j < 4; ++j)
                #pragma unroll
                for (int r = 0; r < 4; ++r) tm = fmaxf(tm, s[h][j][r]);
        #pragma unroll
        for (int off = 32; off >= 1; off >>= 1) tm = fmaxf(tm, __shfl_xor(tm, off));
        const float m_new = fmaxf(m_w, tm);
        const float scale = __expf(m_w - m_new);
        m_w = m_new;
        s_w *= scale;
        #pragma unroll
        for (int h = 0; h < 2; ++h)
            #pragma unroll
            for (int i = 0; i < 8; ++i) {
                acc[h][i][0] *= scale; acc[h][i][1] *= scale;
                acc[h][i][2] *= scale; acc[h][i][3] *= scale;
            }
        float psum = 0.f;
        #pragma unroll
        for (int h = 0; h < 2; ++h)
            #pragma unroll
            for (int j = 0; j < 4; ++j)
                #pragma unroll
                for (int r = 0; r < 4; ++r) {
                    float p = __expf(s[h][j][r] - m_new);
                    psum += p;
                    int qq = h*16 + g*4 + r;
                    ps[wid][(qq*64 + j*16 + m16) ^ ((qq&7)<<3)] = f2bf(p);
                }
        s_w += psum;
        // PV: acc[32q][128c2] += P[32q][64k] * g2[64k][128c2]
        #pragma unroll
        for (int kk = 0; kk < 2; ++kk) {
            s16x8 pa0 = *(const s16x8*)&ps[wid][(m16*64      + kk*32 + g*8) ^ sw16];
            s16x8 pa1 = *(const s16x8*)&ps[wid][((16+m16)*64 + kk*32 + g*8) ^ sw16];
            #pragma unroll
            for (int fc = 0; fc < 8; ++fc) {
                s16x8 gb = *(const s16x8*)&g2s[((fc*16+m16)*64 + kk*32 + g*8) ^ sw16];
                acc[0][fc] = __builtin_amdgcn_mfma_f32_16x16x32_bf16(pa0, gb, acc[0][fc], 0, 0, 0);
                acc[1][fc] = __builtin_amdgcn_mfma_f32_16x16x32_bf16(pa1, gb, acc[1][fc], 0, 0, 0);
            }
        }
    }

    #pragma unroll
    for (int off = 32; off >= 1; off >>= 1) s_w += __shfl_xor(s_w, off);
    if (lane == 0) {
        int idx = b*256 + seg*128 + qb*4 + wid;
        ms[idx*2 + 0] = m_w;
        ms[idx*2 + 1] = s_w;
    }
    const float inv_s = 1.f / s_w;
    u16* op = seg ? outp1 : outp0;
    #pragma unroll
    for (int h = 0; h < 2; ++h)
        #pragma unroll
        for (int fc = 0; fc < 8; ++fc)
            #pragma unroll
            for (int r = 0; r < 4; ++r)
                op[((size_t)b*HWN + q0 + wid*32 + h*16 + g*4 + r)*C2 + fc*16 + m16] =
                    f2bf(acc[h][fc][r] * inv_s);
}

// ---------------- K3: per-batch (M, Z) from 256 (m,s) pairs ----------------
__global__ void k_mz(const float* __restrict__ ms, float* __restrict__ mz)
{
    __shared__ float rmax[4], rsum[4];
    const int b = blockIdx.x, tid = threadIdx.x;
    const int lane = tid & 63, wid = tid >> 6;
    float m = ms[((size_t)b*256 + tid)*2 + 0];
    float s = ms[((size_t)b*256 + tid)*2 + 1];
    float mm = m;
    #pragma unroll
    for (int off = 32; off >= 1; off >>= 1) mm = fmaxf(mm, __shfl_xor(mm, off));
    if (lane == 0) rmax[wid] = mm;
    __syncthreads();
    float M = fmaxf(fmaxf(rmax[0], rmax[1]), fmaxf(rmax[2], rmax[3]));
    float z = s * __expf(m - M);
    #pragma unroll
    for (int off = 32; off >= 1; off >>= 1) z += __shfl_xor(z, off);
    if (lane == 0) rsum[wid] = z;
    __syncthreads();
    if (tid == 0) { mz[b*2] = M; mz[b*2+1] = rsum[0]+rsum[1]+rsum[2]+rsum[3]; }
}

// ---------------- K4: combine k-split partials + final conv + residual --------
__global__ __launch_bounds__(256) void k_outM(
    const u16* __restrict__ outp0, const u16* __restrict__ outp1,
    const float* __restrict__ ms, const float* __restrict__ mz,
    const u16* __restrict__ woutb, const float* __restrict__ b_out,
    const float* __restrict__ x1, float* __restrict__ out)
{
    const int tid  = threadIdx.x;
    const int b    = blockIdx.x >> 6;
    const int q0   = (blockIdx.x & 63) * 64;
    const int wv   = tid >> 6;
    const int lane = tid & 63;
    const int m16  = lane & 15;
    const int g    = lane >> 4;
    const int q    = q0 + wv*16 + m16;

    const float M    = mz[b*2];
    const float invZ = 1.f / mz[b*2+1];
    const int idx5   = (q0 >> 5) + (wv >> 1);   // wave-uniform 32q-group index
    const float a0 = ms[(b*256 + idx5)*2+1]       * __expf(ms[(b*256 + idx5)*2]       - M) * invZ;
    const float a1 = ms[(b*256 + 128 + idx5)*2+1] * __expf(ms[(b*256 + 128 + idx5)*2] - M) * invZ;

    s16x8 bfr[4];
    #pragma unroll
    for (int ks = 0; ks < 4; ++ks) {
        union { s16x8 v; u16 u[8]; } o0, o1, oc;
        o0.v = *(const s16x8*)&outp0[((size_t)b*HWN + q)*C2 + ks*32 + g*8];
        o1.v = *(const s16x8*)&outp1[((size_t)b*HWN + q)*C2 + ks*32 + g*8];
        #pragma unroll
        for (int j = 0; j < 8; ++j)
            oc.u[j] = f2bf(a0*bf2f(o0.u[j]) + a1*bf2f(o1.u[j]));
        bfr[ks] = oc.v;
    }

    f32x4 acc[16];
    #pragma unroll
    for (int cb = 0; cb < 16; ++cb) acc[cb] = (f32x4){0.f,0.f,0.f,0.f};
    #pragma unroll
    for (int ks = 0; ks < 4; ++ks) {
        #pragma unroll
        for (int cb = 0; cb < 16; ++cb) {
            s16x8 afr = *(const s16x8*)&woutb[(size_t)(cb*16 + m16)*C2 + ks*32 + g*8];
            acc[cb] = __builtin_amdgcn_mfma_f32_16x16x32_bf16(afr, bfr[ks], acc[cb], 0, 0, 0);
        }
    }

    #pragma unroll
    for (int cb = 0; cb < 16; ++cb) {
        f32x4 bb = *(const f32x4*)&b_out[cb*16 + g*4];
        #pragma unroll
        for (int r = 0; r < 4; ++r) {
            int co = cb*16 + g*4 + r;
            size_t o = ((size_t)b*CC + co)*HWN + q;
            out[o] = acc[cb][r] + bb[r] + x1[o];
        }
    }
}

extern "C" void kernel_launch(void* const* d_in, const int* in_sizes, int n_in,
                              void* d_out, int out_size, void* d_ws, size_t ws_size,
                              hipStream_t stream)
{
    const float* x1   = (const float*)d_in[0];
    const float* x2   = (const float*)d_in[1];
    const float* w_th = (const float*)d_in[2];
    const float* b_th = (const float*)d_in[3];
    const float* w_pi = (const float*)d_in[4];
    const float* b_pi = (const float*)d_in[5];
    const float* w_g  = (const float*)d_in[6];
    const float* b_g  = (const float*)d_in[7];
    const float* w_out= (const float*)d_in[8];
    const float* b_out= (const float*)d_in[9];
    float* out = (float*)d_out;

    char* ws = (char*)d_ws;
    u16*   e1t  = (u16*)(ws);                    // 8 MiB  bf16 [B][HW][C2]
    u16*   e2t  = (u16*)(ws + 8388608);          // 8 MiB  bf16 [B][HW][C2]
    u16*   g2c  = (u16*)(ws + 16777216);         // 8 MiB  bf16 [B][C2][HW]
    u16*   outp0= (u16*)(ws + 25165824);         // 8 MiB  bf16 seg0 partial
    u16*   outp1= (u16*)(ws + 33554432);         // 8 MiB  bf16 seg1 partial
    float* ms   = (float*)(ws + 41943040);       // 16 KiB f32  [B][256][2]
    float* mz   = (float*)(ws + 41959424);       // 64 B   f32  [B][2]
    u16*   wthb = (u16*)(ws + 41959488);         // 64 KiB bf16 [C2][CC]
    u16*   wpib = (u16*)(ws + 42025024);         // 64 KiB
    u16*   wgb  = (u16*)(ws + 42090560);         // 64 KiB
    u16*   woutb= (u16*)(ws + 42156096);         // 64 KiB bf16 [CC][C2]

    k_wcvt <<<dim3(128), dim3(256), 0, stream>>>(w_th, w_pi, w_g, w_out, wthb, wpib, wgb, woutb);
    k_projM<<<dim3(512), dim3(256), 0, stream>>>(x1, x2, wthb, b_th, wpib, b_pi, wgb, b_g,
                                                 e1t, e2t, g2c);
    k_flash<<<dim3(512), dim3(256), 0, stream>>>(e1t, e2t, g2c, outp0, outp1, ms);
    k_mz   <<<dim3(8),   dim3(256), 0, stream>>>(ms, mz);
    k_outM <<<dim3(512), dim3(256), 0, stream>>>(outp0, outp1, ms, mz, woutb, b_out, x1, out);
}